// Round 2
// baseline (307.160 us; speedup 1.0000x reference)
//
#include <hip/hip_runtime.h>

// ---------------------------------------------------------------------------
// FCGF_point_att2_ican_fc: per-point score -> global BN(1) -> per-segment
// softmax attention pooling -> FC(32,64) -> BN(64).
//
// N = 1,048,576 points x 32 feats (128 MiB fp32), B = 64 segments.
// Two passes over x are structural (softmax weights need global z-stats);
// x fits in 256 MiB L3 so pass 2 is Infinity-Cache-fed.
//
// R2: per-thread-row layout (no inner-loop shuffles; 8 independent float4
// loads/row; w1 in SGPRs), block-end-only reductions, memset folded into
// k_consts (4 dispatches total).
// ---------------------------------------------------------------------------

#define EPS 1e-5f
#define NSB 2048          // blocks in k_stats / k_pool chunks*segs

// workspace layout (bytes)
#define WS_DPART   0          // double[2*NSB]            = 32768 B
#define WS_CONSTS  32768      // float c1, c2
#define WS_OFFS    32800      // int[65] segment offsets
#define WS_GNUM    33280      // float[64*32] sum(e*x)
#define WS_GDEN    41472      // float[64]    sum(e)

// ---------------------------------------------------------------------------
// Pass 1: thread t owns whole rows (grid-stride); z = x_row . w1 + b1.
// 8 independent float4 loads per row; w1 scalarizes to SGPRs (uniform).
// Per-block double partials of (sum z, sum z^2).
__global__ __launch_bounds__(256) void k_stats(const float* __restrict__ x,
                                               const float* __restrict__ w1,
                                               const float* __restrict__ b1,
                                               int N,
                                               double* __restrict__ dpart) {
    const int tid = threadIdx.x;
    const float b1v = b1[0];
    const float4* __restrict__ xv = (const float4*)x;

    const int stride = gridDim.x * 256;
    double accZ = 0.0, accZZ = 0.0;

    for (int row = blockIdx.x * 256 + tid; row < N; row += stride) {
        const float4* __restrict__ rp = xv + (size_t)row * 8;
        float z = b1v;
#pragma unroll
        for (int i = 0; i < 8; ++i) {
            float4 v = rp[i];
            z = fmaf(v.x, w1[4 * i + 0], z);
            z = fmaf(v.y, w1[4 * i + 1], z);
            z = fmaf(v.z, w1[4 * i + 2], z);
            z = fmaf(v.w, w1[4 * i + 3], z);
        }
        accZ  += (double)z;
        accZZ += (double)z * (double)z;
    }

    __shared__ double sZ[256], sZZ[256];
    sZ[tid] = accZ; sZZ[tid] = accZZ;
    __syncthreads();
    for (int s = 128; s > 0; s >>= 1) {
        if (tid < s) { sZ[tid] += sZ[tid + s]; sZZ[tid] += sZZ[tid + s]; }
        __syncthreads();
    }
    if (tid == 0) {
        dpart[2 * blockIdx.x]     = sZ[0];
        dpart[2 * blockIdx.x + 1] = sZZ[0];
    }
}

// ---------------------------------------------------------------------------
// Reduce NSB double partials -> c1 = g1*rsqrt(var+eps), c2 = beta1 - c1*mu;
// prefix-sum lengths; zero gnum/gden (replaces a memset dispatch — ordered
// before k_pool).
__global__ __launch_bounds__(256) void k_consts(const double* __restrict__ dpart,
                                                const int* __restrict__ length,
                                                const float* __restrict__ g1,
                                                const float* __restrict__ beta1,
                                                int N, int B,
                                                float* __restrict__ consts,
                                                int* __restrict__ offs,
                                                float* __restrict__ gnum,
                                                float* __restrict__ gden) {
    __shared__ double sZ[256], sZZ[256];
    const int tid = threadIdx.x;

    for (int i = tid; i < B * 32; i += 256) gnum[i] = 0.f;
    if (tid < B) gden[tid] = 0.f;

    double aZ = 0.0, aZZ = 0.0;
    for (int i = tid; i < NSB; i += 256) {
        aZ  += dpart[2 * i];
        aZZ += dpart[2 * i + 1];
    }
    sZ[tid] = aZ; sZZ[tid] = aZZ;
    __syncthreads();
    for (int s = 128; s > 0; s >>= 1) {
        if (tid < s) { sZ[tid] += sZ[tid + s]; sZZ[tid] += sZZ[tid + s]; }
        __syncthreads();
    }
    if (tid == 0) {
        double mu  = sZ[0] / (double)N;
        double var = sZZ[0] / (double)N - mu * mu;
        float c1 = (float)((double)g1[0] / sqrt(var + (double)EPS));
        float c2 = beta1[0] - (float)(c1 * mu);
        consts[0] = c1;
        consts[1] = c2;
        int o = 0;
        offs[0] = 0;
        for (int b = 0; b < B; ++b) { o += length[b]; offs[b + 1] = o; }
    }
}

// ---------------------------------------------------------------------------
// Pass 2: thread t owns whole rows; s = (c1*z + c2) * rowmean; e = exp(s)
// (segment-max skipped: |s| <~ 2, exactly equivalent after normalization).
// acc[8] float4 per thread; one 6-level wave butterfly at block end, then
// 32 global atomics per wave. Grid: (chunks, seg) — block inside one segment.
__global__ __launch_bounds__(256) void k_pool(const float* __restrict__ x,
                                              const float* __restrict__ w1,
                                              const float* __restrict__ b1,
                                              const float* __restrict__ consts,
                                              const int* __restrict__ offs,
                                              float* __restrict__ gnum,
                                              float* __restrict__ gden) {
    const int tid = threadIdx.x;
    const int b = blockIdx.y;
    const int off = offs[b];
    const int len = offs[b + 1] - off;
    const int nch = gridDim.x;
    const int rpc = (len + nch - 1) / nch;
    const int r0 = blockIdx.x * rpc;
    const int r1 = min(r0 + rpc, len);

    const float b1v = b1[0];
    const float c1 = consts[0], c2 = consts[1];
    const float4* __restrict__ xv = (const float4*)x;

    float4 acc[8];
#pragma unroll
    for (int i = 0; i < 8; ++i) acc[i] = make_float4(0.f, 0.f, 0.f, 0.f);
    float accE = 0.f;

    for (int r = r0 + tid; r < r1; r += 256) {
        const float4* __restrict__ rp = xv + (size_t)(off + r) * 8;
        float4 v[8];
#pragma unroll
        for (int i = 0; i < 8; ++i) v[i] = rp[i];
        float z = b1v, m = 0.f;
#pragma unroll
        for (int i = 0; i < 8; ++i) {
            z = fmaf(v[i].x, w1[4 * i + 0], z);
            z = fmaf(v[i].y, w1[4 * i + 1], z);
            z = fmaf(v[i].z, w1[4 * i + 2], z);
            z = fmaf(v[i].w, w1[4 * i + 3], z);
            m += v[i].x + v[i].y + v[i].z + v[i].w;
        }
        float s = (c1 * z + c2) * m * 0.03125f;
        float e = __expf(s);
#pragma unroll
        for (int i = 0; i < 8; ++i) {
            acc[i].x = fmaf(e, v[i].x, acc[i].x);
            acc[i].y = fmaf(e, v[i].y, acc[i].y);
            acc[i].z = fmaf(e, v[i].z, acc[i].z);
            acc[i].w = fmaf(e, v[i].w, acc[i].w);
        }
        accE += e;
    }

    // one butterfly per wave (once per kernel, not per row)
#pragma unroll
    for (int msk = 1; msk < 64; msk <<= 1) {
#pragma unroll
        for (int i = 0; i < 8; ++i) {
            acc[i].x += __shfl_xor(acc[i].x, msk);
            acc[i].y += __shfl_xor(acc[i].y, msk);
            acc[i].z += __shfl_xor(acc[i].z, msk);
            acc[i].w += __shfl_xor(acc[i].w, msk);
        }
        accE += __shfl_xor(accE, msk);
    }
    const int lane = tid & 63;
    if (lane < 8) {
        atomicAdd(&gnum[b * 32 + lane * 4 + 0], acc[lane].x);
        atomicAdd(&gnum[b * 32 + lane * 4 + 1], acc[lane].y);
        atomicAdd(&gnum[b * 32 + lane * 4 + 2], acc[lane].z);
        atomicAdd(&gnum[b * 32 + lane * 4 + 3], acc[lane].w);
        if (lane == 0) atomicAdd(&gden[b], accE);
    }
}

// ---------------------------------------------------------------------------
// Epilogue: pooled = num/(den*len); h = pooled @ W2 + b2; BN over B rows.
__global__ __launch_bounds__(256) void k_head(const float* __restrict__ gnum,
                                              const float* __restrict__ gden,
                                              const int* __restrict__ length,
                                              const float* __restrict__ W2,
                                              const float* __restrict__ b2,
                                              const float* __restrict__ g2,
                                              const float* __restrict__ beta2,
                                              float* __restrict__ out, int B) {
    __shared__ float pooled[64 * 32];
    __shared__ float h[64 * 64];
    __shared__ float mu2[64], isd[64];
    const int tid = threadIdx.x;

    for (int i = tid; i < B * 32; i += 256) {
        int bb = i >> 5;
        pooled[i] = gnum[i] / (gden[bb] * (float)length[bb]);
    }
    __syncthreads();

    const int j = tid & 63;       // output feature
    const int g = tid >> 6;       // 0..3 row group
    for (int r = 0; r < 16; ++r) {
        int bb = g * 16 + r;
        if (bb < B) {
            float hv = b2[j];
            for (int k = 0; k < 32; ++k) hv += pooled[bb * 32 + k] * W2[k * 64 + j];
            h[bb * 64 + j] = hv;
        }
    }
    __syncthreads();

    if (tid < 64) {
        float m = 0.f;
        for (int bb = 0; bb < B; ++bb) m += h[bb * 64 + tid];
        m /= (float)B;
        float v = 0.f;
        for (int bb = 0; bb < B; ++bb) { float d = h[bb * 64 + tid] - m; v += d * d; }
        v /= (float)B;
        mu2[tid] = m;
        isd[tid] = rsqrtf(v + EPS);
    }
    __syncthreads();

    for (int r = 0; r < 16; ++r) {
        int bb = g * 16 + r;
        if (bb < B) {
            int idx = bb * 64 + j;
            out[idx] = g2[j] * (h[idx] - mu2[j]) * isd[j] + beta2[j];
        }
    }
}

// ---------------------------------------------------------------------------
extern "C" void kernel_launch(void* const* d_in, const int* in_sizes, int n_in,
                              void* d_out, int out_size, void* d_ws, size_t ws_size,
                              hipStream_t stream) {
    const float* x      = (const float*)d_in[0];
    const int*   length = (const int*)  d_in[1];
    const float* w1     = (const float*)d_in[2];
    const float* b1     = (const float*)d_in[3];
    const float* g1     = (const float*)d_in[4];
    const float* beta1  = (const float*)d_in[5];
    const float* W2     = (const float*)d_in[6];
    const float* b2     = (const float*)d_in[7];
    const float* g2     = (const float*)d_in[8];
    const float* beta2  = (const float*)d_in[9];
    float* out = (float*)d_out;

    const int N = in_sizes[0] / 32;
    const int B = in_sizes[1];

    char* ws = (char*)d_ws;
    double* dpart  = (double*)(ws + WS_DPART);
    float*  consts = (float*) (ws + WS_CONSTS);
    int*    offs   = (int*)   (ws + WS_OFFS);
    float*  gnum   = (float*) (ws + WS_GNUM);
    float*  gden   = (float*) (ws + WS_GDEN);

    k_stats <<<NSB, 256, 0, stream>>>(x, w1, b1, N, dpart);
    k_consts<<<1,   256, 0, stream>>>(dpart, length, g1, beta1, N, B,
                                      consts, offs, gnum, gden);
    k_pool  <<<dim3(32, B), 256, 0, stream>>>(x, w1, b1, consts, offs, gnum, gden);
    k_head  <<<1,   256, 0, stream>>>(gnum, gden, length, W2, b2, g2, beta2, out, B);
}

// Round 3
// 249.955 us; speedup vs baseline: 1.2289x; 1.2289x over previous
//
#include <hip/hip_runtime.h>

// ---------------------------------------------------------------------------
// FCGF_point_att2_ican_fc: per-point score -> global BN(1) -> per-segment
// softmax attention pooling -> FC(32,64) -> BN(64).
//
// N = 1,048,576 points x 32 feats (128 MiB fp32), B = 64 segments.
// Two passes over x are structural (softmax weights need global z-stats).
//
// R3: kill the k_pool scratch spill. R2's final reduction used acc[lane]
// (dynamic register-array index) which forced acc[]/v[] into scratch:
// VGPR_Count=40 + 105 MB WRITE_SIZE = per-row scratch RMW. Now: all
// register arrays statically indexed (full unroll), per-wave results go
// through LDS (static stores from lane 0), one 33-value atomic set per
// block. __launch_bounds__(256,4) = 128-VGPR cap for the ~80-reg live set.
// ---------------------------------------------------------------------------

#define EPS 1e-5f
#define NSB 1024          // blocks in k_stats
#define CHUNKS 16         // k_pool chunks per segment

// workspace layout (bytes)
#define WS_DPART   0          // double[2*NSB]            = 16384 B
#define WS_CONSTS  16384      // float c1, c2
#define WS_OFFS    16416      // int[65] segment offsets
#define WS_GNUM    16896      // float[64*32] sum(e*x)
#define WS_GDEN    25088      // float[64]    sum(e)

// ---------------------------------------------------------------------------
// Pass 1: thread owns whole rows (grid-stride); z = x_row . w1 + b1.
// Per-block double partials of (sum z, sum z^2).
__global__ __launch_bounds__(256, 4) void k_stats(const float* __restrict__ x,
                                                  const float* __restrict__ w1,
                                                  const float* __restrict__ b1,
                                                  int N,
                                                  double* __restrict__ dpart) {
    const int tid = threadIdx.x;
    const float b1v = b1[0];
    const float4* __restrict__ xv = (const float4*)x;

    const int stride = gridDim.x * 256;
    double accZ = 0.0, accZZ = 0.0;

    for (int row = blockIdx.x * 256 + tid; row < N; row += stride) {
        const float4* __restrict__ rp = xv + (size_t)row * 8;
        float4 v[8];
#pragma unroll
        for (int i = 0; i < 8; ++i) v[i] = rp[i];
        float z = b1v;
#pragma unroll
        for (int i = 0; i < 8; ++i) {
            z = fmaf(v[i].x, w1[4 * i + 0], z);
            z = fmaf(v[i].y, w1[4 * i + 1], z);
            z = fmaf(v[i].z, w1[4 * i + 2], z);
            z = fmaf(v[i].w, w1[4 * i + 3], z);
        }
        accZ  += (double)z;
        accZZ += (double)z * (double)z;
    }

    __shared__ double sZ[256], sZZ[256];
    sZ[tid] = accZ; sZZ[tid] = accZZ;
    __syncthreads();
    for (int s = 128; s > 0; s >>= 1) {
        if (tid < s) { sZ[tid] += sZ[tid + s]; sZZ[tid] += sZZ[tid + s]; }
        __syncthreads();
    }
    if (tid == 0) {
        dpart[2 * blockIdx.x]     = sZ[0];
        dpart[2 * blockIdx.x + 1] = sZZ[0];
    }
}

// ---------------------------------------------------------------------------
// Reduce NSB double partials -> c1 = g1*rsqrt(var+eps), c2 = beta1 - c1*mu;
// prefix-sum lengths; zero gnum/gden (ordered before k_pool on the stream).
__global__ __launch_bounds__(256) void k_consts(const double* __restrict__ dpart,
                                                const int* __restrict__ length,
                                                const float* __restrict__ g1,
                                                const float* __restrict__ beta1,
                                                int N, int B,
                                                float* __restrict__ consts,
                                                int* __restrict__ offs,
                                                float* __restrict__ gnum,
                                                float* __restrict__ gden) {
    __shared__ double sZ[256], sZZ[256];
    const int tid = threadIdx.x;

    for (int i = tid; i < B * 32; i += 256) gnum[i] = 0.f;
    if (tid < B) gden[tid] = 0.f;

    double aZ = 0.0, aZZ = 0.0;
    for (int i = tid; i < NSB; i += 256) {
        aZ  += dpart[2 * i];
        aZZ += dpart[2 * i + 1];
    }
    sZ[tid] = aZ; sZZ[tid] = aZZ;
    __syncthreads();
    for (int s = 128; s > 0; s >>= 1) {
        if (tid < s) { sZ[tid] += sZ[tid + s]; sZZ[tid] += sZZ[tid + s]; }
        __syncthreads();
    }
    if (tid == 0) {
        double mu  = sZ[0] / (double)N;
        double var = sZZ[0] / (double)N - mu * mu;
        float c1 = (float)((double)g1[0] / sqrt(var + (double)EPS));
        float c2 = beta1[0] - (float)(c1 * mu);
        consts[0] = c1;
        consts[1] = c2;
        int o = 0;
        offs[0] = 0;
        for (int b = 0; b < B; ++b) { o += length[b]; offs[b + 1] = o; }
    }
}

// ---------------------------------------------------------------------------
// Pass 2: thread owns whole rows; s = (c1*z + c2) * rowmean; e = exp(s)
// (segment-max skipped: |s| <~ 3, exactly equivalent after normalization).
// All register arrays statically indexed (full unroll) — NO acc[lane]!
// Wave butterfly -> lane-0 static stores to LDS -> 33 atomics per block.
// Grid: (CHUNKS, seg) — each block entirely inside one segment.
__global__ __launch_bounds__(256, 4) void k_pool(const float* __restrict__ x,
                                                 const float* __restrict__ w1,
                                                 const float* __restrict__ b1,
                                                 const float* __restrict__ consts,
                                                 const int* __restrict__ offs,
                                                 float* __restrict__ gnum,
                                                 float* __restrict__ gden) {
    const int tid = threadIdx.x;
    const int b = blockIdx.y;
    const int off = offs[b];
    const int len = offs[b + 1] - off;
    const int rpc = (len + CHUNKS - 1) / CHUNKS;
    const int r0 = blockIdx.x * rpc;
    const int r1 = min(r0 + rpc, len);

    const float b1v = b1[0];
    const float c1 = consts[0], c2 = consts[1];
    const float4* __restrict__ xv = (const float4*)x;

    float4 acc[8];
#pragma unroll
    for (int i = 0; i < 8; ++i) acc[i] = make_float4(0.f, 0.f, 0.f, 0.f);
    float accE = 0.f;

    for (int r = r0 + tid; r < r1; r += 256) {
        const float4* __restrict__ rp = xv + (size_t)(off + r) * 8;
        float4 v[8];
#pragma unroll
        for (int i = 0; i < 8; ++i) v[i] = rp[i];
        float z = b1v, m = 0.f;
#pragma unroll
        for (int i = 0; i < 8; ++i) {
            z = fmaf(v[i].x, w1[4 * i + 0], z);
            z = fmaf(v[i].y, w1[4 * i + 1], z);
            z = fmaf(v[i].z, w1[4 * i + 2], z);
            z = fmaf(v[i].w, w1[4 * i + 3], z);
            m += v[i].x + v[i].y + v[i].z + v[i].w;
        }
        float s = (c1 * z + c2) * m * 0.03125f;
        float e = __expf(s);
#pragma unroll
        for (int i = 0; i < 8; ++i) {
            acc[i].x = fmaf(e, v[i].x, acc[i].x);
            acc[i].y = fmaf(e, v[i].y, acc[i].y);
            acc[i].z = fmaf(e, v[i].z, acc[i].z);
            acc[i].w = fmaf(e, v[i].w, acc[i].w);
        }
        accE += e;
    }

    // wave butterfly (static indices only)
#pragma unroll
    for (int msk = 1; msk < 64; msk <<= 1) {
#pragma unroll
        for (int i = 0; i < 8; ++i) {
            acc[i].x += __shfl_xor(acc[i].x, msk);
            acc[i].y += __shfl_xor(acc[i].y, msk);
            acc[i].z += __shfl_xor(acc[i].z, msk);
            acc[i].w += __shfl_xor(acc[i].w, msk);
        }
        accE += __shfl_xor(accE, msk);
    }

    // per-wave lane 0 -> LDS (static stores), cross-wave sum, 33 atomics/block
    __shared__ float sred[4][33];
    const int wave = tid >> 6;
    const int lane = tid & 63;
    if (lane == 0) {
#pragma unroll
        for (int i = 0; i < 8; ++i) {
            sred[wave][4 * i + 0] = acc[i].x;
            sred[wave][4 * i + 1] = acc[i].y;
            sred[wave][4 * i + 2] = acc[i].z;
            sred[wave][4 * i + 3] = acc[i].w;
        }
        sred[wave][32] = accE;
    }
    __syncthreads();
    if (tid < 33) {
        float s = sred[0][tid] + sred[1][tid] + sred[2][tid] + sred[3][tid];
        if (tid < 32) atomicAdd(&gnum[b * 32 + tid], s);
        else          atomicAdd(&gden[b], s);
    }
}

// ---------------------------------------------------------------------------
// Epilogue: pooled = num/(den*len); h = pooled @ W2 + b2; BN over B rows.
__global__ __launch_bounds__(256) void k_head(const float* __restrict__ gnum,
                                              const float* __restrict__ gden,
                                              const int* __restrict__ length,
                                              const float* __restrict__ W2,
                                              const float* __restrict__ b2,
                                              const float* __restrict__ g2,
                                              const float* __restrict__ beta2,
                                              float* __restrict__ out, int B) {
    __shared__ float pooled[64 * 32];
    __shared__ float h[64 * 64];
    __shared__ float mu2[64], isd[64];
    const int tid = threadIdx.x;

    for (int i = tid; i < B * 32; i += 256) {
        int bb = i >> 5;
        pooled[i] = gnum[i] / (gden[bb] * (float)length[bb]);
    }
    __syncthreads();

    const int j = tid & 63;       // output feature
    const int g = tid >> 6;       // 0..3 row group
    for (int r = 0; r < 16; ++r) {
        int bb = g * 16 + r;
        if (bb < B) {
            float hv = b2[j];
            for (int k = 0; k < 32; ++k) hv += pooled[bb * 32 + k] * W2[k * 64 + j];
            h[bb * 64 + j] = hv;
        }
    }
    __syncthreads();

    if (tid < 64) {
        float m = 0.f;
        for (int bb = 0; bb < B; ++bb) m += h[bb * 64 + tid];
        m /= (float)B;
        float v = 0.f;
        for (int bb = 0; bb < B; ++bb) { float d = h[bb * 64 + tid] - m; v += d * d; }
        v /= (float)B;
        mu2[tid] = m;
        isd[tid] = rsqrtf(v + EPS);
    }
    __syncthreads();

    for (int r = 0; r < 16; ++r) {
        int bb = g * 16 + r;
        if (bb < B) {
            int idx = bb * 64 + j;
            out[idx] = g2[j] * (h[idx] - mu2[j]) * isd[j] + beta2[j];
        }
    }
}

// ---------------------------------------------------------------------------
extern "C" void kernel_launch(void* const* d_in, const int* in_sizes, int n_in,
                              void* d_out, int out_size, void* d_ws, size_t ws_size,
                              hipStream_t stream) {
    const float* x      = (const float*)d_in[0];
    const int*   length = (const int*)  d_in[1];
    const float* w1     = (const float*)d_in[2];
    const float* b1     = (const float*)d_in[3];
    const float* g1     = (const float*)d_in[4];
    const float* beta1  = (const float*)d_in[5];
    const float* W2     = (const float*)d_in[6];
    const float* b2     = (const float*)d_in[7];
    const float* g2     = (const float*)d_in[8];
    const float* beta2  = (const float*)d_in[9];
    float* out = (float*)d_out;

    const int N = in_sizes[0] / 32;
    const int B = in_sizes[1];

    char* ws = (char*)d_ws;
    double* dpart  = (double*)(ws + WS_DPART);
    float*  consts = (float*) (ws + WS_CONSTS);
    int*    offs   = (int*)   (ws + WS_OFFS);
    float*  gnum   = (float*) (ws + WS_GNUM);
    float*  gden   = (float*) (ws + WS_GDEN);

    k_stats <<<NSB, 256, 0, stream>>>(x, w1, b1, N, dpart);
    k_consts<<<1,   256, 0, stream>>>(dpart, length, g1, beta1, N, B,
                                      consts, offs, gnum, gden);
    k_pool  <<<dim3(CHUNKS, B), 256, 0, stream>>>(x, w1, b1, consts, offs, gnum, gden);
    k_head  <<<1,   256, 0, stream>>>(gnum, gden, length, W2, b2, g2, beta2, out, B);
}